// Round 3
// baseline (889.956 us; speedup 1.0000x reference)
//
#include <hip/hip_runtime.h>

// FootprintExtruder: extrude [H,W] height/seg maps into [Z,H,W] int32 volume.
#define L1_HEIGHT 0      // z < 0 never true -> branch dead
#define ROOF_HEIGHT 1
#define ROOF_ID_OFFSET 1
#define FP_ID_MIN 100
#define FP_ID_MAX 5000
#define MAX_HEIGHT 384
#define HH 768
#define WW 768
#define HW (HH * WW)         // 589824 ints per plane
#define HW4 (HW / 4)         // 147456 int4 per plane
#define N4 (MAX_HEIGHT * HW4) // 56,623,104 int4 total

// Fill-mimic structure: 1-D grid, linear window-stride sweep, exactly like
// __amd_rocclr_fillBufferAligned (which sustains 6.3 TB/s on this buffer).
// 8192 blocks x 256 thr = 2,097,152 threads; N4 / 2,097,152 = 27 exactly.
#define NBLOCKS 8192
#define NTHREADS (NBLOCKS * 256)
#define ITERS (N4 / NTHREADS)   // 27, no remainder

typedef int vint4 __attribute__((ext_vector_type(4)));

__device__ __forceinline__ int voxel(int z, int hf, int seg) {
    // z < L1_HEIGHT(=0) impossible. roof voxel: z == hf-1 and seg is footprint.
    bool is_fp = (seg >= FP_ID_MIN) & (seg < FP_ID_MAX);
    int v = ((z == hf - 1) & is_fp) ? seg + ROOF_ID_OFFSET : seg;
    return (z < hf) ? v : 0;
}

__global__ __launch_bounds__(256) void extrude_kernel(
        const int* __restrict__ hf_map, const int* __restrict__ seg_map,
        int* __restrict__ out) {
    const unsigned g = blockIdx.x * 256 + threadIdx.x;

    #pragma unroll 3
    for (int k = 0; k < ITERS; ++k) {
        // Linear int4 index; whole grid covers a contiguous 32 MB window per
        // iteration and sweeps the volume front-to-back (fill-identical).
        const unsigned idx = g + (unsigned)k * NTHREADS;
        const unsigned z   = idx / HW4;          // magic-mul, ~3 VALU
        const unsigned p4  = idx - z * HW4;      // plane int4 offset
        const int*     pp  = (const int*)(hf_map  + (size_t)p4 * 4);
        const int*     sp  = (const int*)(seg_map + (size_t)p4 * 4);

        const vint4 hf4 = *(const vint4*)pp;     // L2/LLC-resident (4.7 MB in)
        const vint4 sg4 = *(const vint4*)sp;

        vint4 o;
        o.x = voxel((int)z, hf4.x, sg4.x);
        o.y = voxel((int)z, hf4.y, sg4.y);
        o.z = voxel((int)z, hf4.z, sg4.z);
        o.w = voxel((int)z, hf4.w, sg4.w);

        *(vint4*)(out + (size_t)idx * 4) = o;    // plain store, linear stream
    }
}

extern "C" void kernel_launch(void* const* d_in, const int* in_sizes, int n_in,
                              void* d_out, int out_size, void* d_ws, size_t ws_size,
                              hipStream_t stream) {
    const int* hf  = (const int*)d_in[0];   // height_field [1,768,768] int32
    const int* seg = (const int*)d_in[1];   // seg_map      [1,768,768] int32
    int* out = (int*)d_out;                 // [1,384,768,768] int32

    extrude_kernel<<<dim3(NBLOCKS), 256, 0, stream>>>(hf, seg, out);
}